// Round 1
// baseline (292.560 us; speedup 1.0000x reference)
//
#include <hip/hip_runtime.h>
#include <math.h>

// x [64,4096,64] fp32, embedding [512,64] fp32
#define N_ROWS   262144
#define DIM      64
#define KCODES   512
#define MT       64          // rows per block
#define NTHREADS 256
#define NBLOCKS  (N_ROWS / MT)   // 4096
#define XS_STRIDE 68         // floats  (272 B, 16-B aligned)
#define ES_STRIDE 72         // bf16    (144 B, 16-B aligned)
#define CHUNK    64          // codes per LDS chunk
#define NCHUNK   (KCODES / CHUNK)  // 8
#define MARGIN   2e-3f       // flag threshold; split error bound ~5e-4

typedef float f32x4 __attribute__((ext_vector_type(4)));
typedef short s16x8 __attribute__((ext_vector_type(8)));

// ws layout (bytes):
//   0       esq[512]        f32   (2048)
//   2048    counts[512]     int   (2048)
//   4096    lossAdj         f32   (4)      fused cleanup's rare additions
//   4608    eh[512*64]      bf16  (65536)
//   70144   el[512*64]      bf16  (65536)
//   168448  idx[262144]     u16   (524288)
//   692736  lossPart[4096]  f32   (16384)

__device__ __forceinline__ unsigned short f2bf(float f) {
    unsigned u = __float_as_uint(f);
    unsigned r = u + 0x7fffu + ((u >> 16) & 1u);   // RNE
    return (unsigned short)(r >> 16);
}
__device__ __forceinline__ float bf2f(unsigned short h) {
    return __uint_as_float(((unsigned)h) << 16);
}

__global__ __launch_bounds__(64) void vq_prep(const float* __restrict__ emb,
                                              float* __restrict__ esq,
                                              int* __restrict__ counts,
                                              float* __restrict__ lossAdj,
                                              unsigned short* __restrict__ eh,
                                              unsigned short* __restrict__ el) {
    int k = blockIdx.x * 64 + threadIdx.x;     // 8 blocks x 64 = 512
    const float* e = emb + (size_t)k * DIM;
    float s = 0.f;
    #pragma unroll
    for (int d = 0; d < DIM; ++d) s += e[d] * e[d];   // identical to round-1 prep
    esq[k] = s;
    counts[k] = 0;
    #pragma unroll
    for (int d = 0; d < DIM; ++d) {
        float v = e[d];
        unsigned short h = f2bf(v);
        eh[k * DIM + d] = h;
        el[k * DIM + d] = f2bf(v - bf2f(h));
    }
    if (k == 0) *lossAdj = 0.f;
}

__global__ __launch_bounds__(NTHREADS, 4) void vq_main(
    const float* __restrict__ x, const float* __restrict__ emb,
    const float* __restrict__ g_esq,
    const unsigned short* __restrict__ eh_g, const unsigned short* __restrict__ el_g,
    unsigned short* __restrict__ g_idx, float* __restrict__ g_lossPart,
    float* __restrict__ lossAdj, float* __restrict__ out)
{
    __shared__ float xs[MT * XS_STRIDE];                  // 17.4 KB, row-major x tile
    __shared__ unsigned short ehs[CHUNK * ES_STRIDE];     // 9.2 KB codebook chunk hi
    __shared__ unsigned short els[CHUNK * ES_STRIDE];     // 9.2 KB codebook chunk lo
    __shared__ float esq_s[KCODES];                       // 2 KB
    __shared__ int   idx_s[MT];
    __shared__ int   flg_s[MT];
    __shared__ int   flist[MT];
    __shared__ int   nflag;
    __shared__ float wred[4];

    const int tid  = threadIdx.x;
    const int R0   = blockIdx.x * MT;
    const int w    = tid >> 6;          // wave 0..3 -> rows w*16..w*16+15
    const int lane = tid & 63;
    const int m    = lane & 15;         // A-frag row / B-frag col / C col
    const int q    = lane >> 4;         // quad: k-run selector / C row group

    // ---- stage x tile (coalesced float4, row-major stride 68) ----
    #pragma unroll
    for (int i = 0; i < 4; ++i) {
        int flat = tid + NTHREADS * i;          // 0..1023
        int r  = flat >> 4;
        int qc = flat & 15;
        f32x4 v = *(const f32x4*)&x[(size_t)(R0 + r) * DIM + 4 * qc];
        *(f32x4*)&xs[r * XS_STRIDE + 4 * qc] = v;
    }
    esq_s[tid]       = g_esq[tid];
    esq_s[tid + 256] = g_esq[tid + 256];
    if (tid == 0) nflag = 0;
    __syncthreads();

    // ---- A-frags (register-resident): rows w*16+m, k = kc*32 + q*8 + t ----
    s16x8 axh[2], axl[2];
    const int lrow = w * 16 + m;
    #pragma unroll
    for (int kc = 0; kc < 2; ++kc) {
        f32x4 xv0 = *(const f32x4*)&xs[lrow * XS_STRIDE + kc * 32 + q * 8];
        f32x4 xv1 = *(const f32x4*)&xs[lrow * XS_STRIDE + kc * 32 + q * 8 + 4];
        s16x8 h, l;
        #pragma unroll
        for (int t = 0; t < 8; ++t) {
            float v = (t < 4) ? xv0[t] : xv1[t - 4];
            unsigned short hb = f2bf(v);
            h[t] = (short)hb;
            l[t] = (short)f2bf(v - bf2f(hb));
        }
        axh[kc] = h; axl[kc] = l;
    }

    // ---- running argmin + second-best state (per lane: 4 C-rows) ----
    float b1[4], b2[4]; int i1[4];
    #pragma unroll
    for (int r = 0; r < 4; ++r) { b1[r] = 3.4e38f; b2[r] = 3.4e38f; i1[r] = 0; }

    // ---- 8 chunks of 64 codes; acc released per-chunk (regs stay small) ----
    for (int c = 0; c < NCHUNK; ++c) {
        if (c) __syncthreads();                          // prior chunk reads done
        #pragma unroll
        for (int i = 0; i < 2; ++i) {                    // stage chunk: coalesced 16B
            int ch = tid + NTHREADS * i;                 // 0..511
            int rl = ch >> 3, off = (ch & 7) * 8;
            size_t gofs = (size_t)(c * CHUNK + rl) * DIM + off;
            *(s16x8*)&ehs[rl * ES_STRIDE + off] = *(const s16x8*)&eh_g[gofs];
            *(s16x8*)&els[rl * ES_STRIDE + off] = *(const s16x8*)&el_g[gofs];
        }
        __syncthreads();

        f32x4 acc[4];
        #pragma unroll
        for (int ct = 0; ct < 4; ++ct) acc[ct] = (f32x4){0.f, 0.f, 0.f, 0.f};
        #pragma unroll
        for (int ct = 0; ct < 4; ++ct) {
            #pragma unroll
            for (int kc = 0; kc < 2; ++kc) {
                const int bofs = (ct * 16 + m) * ES_STRIDE + kc * 32 + q * 8;
                s16x8 bh = *(const s16x8*)&ehs[bofs];
                s16x8 bl = *(const s16x8*)&els[bofs];
                acc[ct] = __builtin_amdgcn_mfma_f32_16x16x32_bf16(axh[kc], bh, acc[ct], 0, 0, 0);
                acc[ct] = __builtin_amdgcn_mfma_f32_16x16x32_bf16(axl[kc], bh, acc[ct], 0, 0, 0);
                acc[ct] = __builtin_amdgcn_mfma_f32_16x16x32_bf16(axh[kc], bl, acc[ct], 0, 0, 0);
            }
        }
        // ---- per-chunk argmin update (same col order / math as full-acc version) ----
        #pragma unroll
        for (int ct = 0; ct < 4; ++ct) {
            int col = c * CHUNK + ct * 16 + m;           // ascending in (c,ct)
            float e2 = esq_s[col];
            #pragma unroll
            for (int r = 0; r < 4; ++r) {
                float dist = e2 - 2.f * acc[ct][r];
                if (dist < b1[r]) { b2[r] = b1[r]; b1[r] = dist; i1[r] = col; }
                else if (dist < b2[r]) b2[r] = dist;
            }
        }
    }

    // ---- butterfly within 16-lane group (C layout: row=q*4+r, col covered above) ----
    #pragma unroll
    for (int s = 1; s < 16; s <<= 1) {
        #pragma unroll
        for (int r = 0; r < 4; ++r) {
            float ob1 = __shfl_xor(b1[r], s);
            int   oi1 = __shfl_xor(i1[r], s);
            float ob2 = __shfl_xor(b2[r], s);
            bool owin = (ob1 < b1[r]) || (ob1 == b1[r] && oi1 < i1[r]);
            float lb1 = owin ? b1[r] : ob1;              // loser's best = new 2nd candidate
            b2[r] = fminf(fminf(b2[r], ob2), lb1);
            if (owin) { b1[r] = ob1; i1[r] = oi1; }
        }
    }
    if (m == 0) {
        #pragma unroll
        for (int r = 0; r < 4; ++r) {
            int lrw = w * 16 + q * 4 + r;
            idx_s[lrw] = i1[r];
            flg_s[lrw] = (b2[r] - b1[r] < MARGIN) ? 1 : 0;
        }
    }
    __syncthreads();

    // flagged rows -> in-block list; unflagged -> index out
    if (tid < MT) {
        if (flg_s[tid]) { int p = atomicAdd(&nflag, 1); flist[p] = tid; }
        else g_idx[R0 + tid] = (unsigned short)idx_s[tid];
    }

    // ---- epilogue: q_st + loss for unflagged rows (round-1 op order) ----
    const int r  = tid >> 2;
    const int d0 = (tid & 3) * 16;
    float lpart = 0.f;
    if (!flg_s[r]) {
        const int ki = idx_s[r];
        const float* erow = emb + (size_t)ki * DIM;
        #pragma unroll
        for (int s4 = 0; s4 < 4; ++s4) {
            int d = d0 + 4 * s4;
            f32x4 e4 = *(const f32x4*)&erow[d];
            f32x4 xv = *(const f32x4*)&xs[r * XS_STRIDE + d];
            float f0 = e4.x - xv.x, f1 = e4.y - xv.y, f2 = e4.z - xv.z, f3 = e4.w - xv.w;
            f32x4 o = {xv.x + f0, xv.y + f1, xv.z + f2, xv.w + f3};
            *(f32x4*)&out[(size_t)(R0 + r) * DIM + d] = o;
            lpart += f0*f0 + f1*f1 + f2*f2 + f3*f3;
        }
    }
    #pragma unroll
    for (int off = 32; off > 0; off >>= 1) lpart += __shfl_down(lpart, off);
    if ((tid & 63) == 0) wred[tid >> 6] = lpart;
    __syncthreads();                                     // wred + nflag/flist ready
    if (tid == 0) g_lossPart[blockIdx.x] = wred[0] + wred[1] + wred[2] + wred[3];

    // ---- fused cleanup: exact fp32 re-resolution of this block's flagged rows ----
    // replicates the original vq_cleanup math bit-for-bit (reads x/emb from global)
    for (int fi = w; fi < nflag; fi += 4) {
        int row = R0 + flist[fi];
        const float* xr = &x[(size_t)row * DIM];
        float best = 3.4e38f; int bidx = 0;
        #pragma unroll
        for (int j = 0; j < 8; ++j) {
            int cc = lane * 8 + j;
            const float* er = &emb[(size_t)cc * DIM];
            float dot = 0.f;
            #pragma unroll
            for (int d = 0; d < DIM; ++d) dot = fmaf(xr[d], er[d], dot);
            float dist = g_esq[cc] - 2.f * dot;          // round-1 formula/order
            if (dist < best) { best = dist; bidx = cc; }
        }
        #pragma unroll
        for (int s = 1; s < 64; s <<= 1) {
            float ob = __shfl_xor(best, s);
            int   oi = __shfl_xor(bidx, s);
            if (ob < best || (ob == best && oi < bidx)) { best = ob; bidx = oi; }
        }
        float xv = xr[lane];
        float ev = emb[(size_t)bidx * DIM + lane];
        float f  = ev - xv;
        out[(size_t)row * DIM + lane] = xv + f;
        float lp = f * f;
        #pragma unroll
        for (int s = 1; s < 64; s <<= 1) lp += __shfl_xor(lp, s);
        if (lane == 0) {
            atomicAdd(lossAdj, lp);                      // rare (~tens of rows total)
            g_idx[row] = (unsigned short)bidx;
        }
    }
}

// Low-contention histogram: LDS per-block, then <=512 global adds per block.
__global__ __launch_bounds__(256) void vq_hist(const unsigned short* __restrict__ g_idx,
                                               int* __restrict__ counts) {
    __shared__ int h[KCODES];
    int t = threadIdx.x;
    h[t] = 0; h[t + 256] = 0;
    __syncthreads();
    const unsigned short* p = g_idx + (size_t)blockIdx.x * 4096;
    #pragma unroll
    for (int i = 0; i < 16; ++i)
        atomicAdd(&h[p[t + 256 * i]], 1);
    __syncthreads();
    int v0 = h[t], v1 = h[t + 256];
    if (v0) atomicAdd(&counts[t], v0);
    if (v1) atomicAdd(&counts[t + 256], v1);
}

__global__ __launch_bounds__(512) void vq_final(const int* __restrict__ counts,
                                                const float* __restrict__ lossPart,
                                                const float* __restrict__ lossAdj,
                                                float* __restrict__ out) {
    __shared__ float redp[8];
    __shared__ float redl[8];
    int k = threadIdx.x;
    float p = (float)counts[k] * (1.f / 262144.f);
    float t = p * logf(p + 1e-10f);
    float l = 0.f;
    #pragma unroll
    for (int i = 0; i < 8; ++i) l += lossPart[k + 512 * i];
    #pragma unroll
    for (int off = 32; off > 0; off >>= 1) {
        t += __shfl_down(t, off);
        l += __shfl_down(l, off);
    }
    if ((k & 63) == 0) { redp[k >> 6] = t; redl[k >> 6] = l; }
    __syncthreads();
    if (k == 0) {
        float s = 0.f, ls = 0.f;
        #pragma unroll
        for (int i = 0; i < 8; ++i) { s += redp[i]; ls += redl[i]; }
        out[16777216] = (ls + *lossAdj) * (0.25f / 16777216.f);
        out[16777217] = expf(-s);
    }
}

extern "C" void kernel_launch(void* const* d_in, const int* in_sizes, int n_in,
                              void* d_out, int out_size, void* d_ws, size_t ws_size,
                              hipStream_t stream) {
    const float* x   = (const float*)d_in[0];
    const float* emb = (const float*)d_in[1];
    float* out = (float*)d_out;

    char* ws = (char*)d_ws;
    float*          esq      = (float*)(ws + 0);
    int*            counts   = (int*)(ws + 2048);
    float*          lossAdj  = (float*)(ws + 4096);
    unsigned short* eh       = (unsigned short*)(ws + 4608);
    unsigned short* el       = (unsigned short*)(ws + 70144);
    unsigned short* gidx     = (unsigned short*)(ws + 168448);
    float*          lossPart = (float*)(ws + 692736);

    vq_prep<<<8, 64, 0, stream>>>(emb, esq, counts, lossAdj, eh, el);
    vq_main<<<NBLOCKS, NTHREADS, 0, stream>>>(x, emb, esq, eh, el,
                                              gidx, lossPart, lossAdj, out);
    vq_hist<<<64, 256, 0, stream>>>(gidx, counts);
    vq_final<<<1, 512, 0, stream>>>(counts, lossPart, lossAdj, out);
}